// Round 3
// baseline (415.951 us; speedup 1.0000x reference)
//
#include <hip/hip_runtime.h>
#include <math.h>

#define B 32
#define LQ 512
#define LK 2048
#define D 768
#define D4 192  // D/4 float4s per row

// ---------------- K1: s_sum[b,d] = sum_q sentence[b,q,d] ----------------
// grid (32, 8), block 192 (one float4 column per thread), atomicAdd partials.
__global__ __launch_bounds__(192) void k_sum_sent(const float4* __restrict__ sent,
                                                  float* __restrict__ s_sum) {
    int b = blockIdx.x, qc = blockIdx.y;
    int d4 = threadIdx.x;  // 0..191
    const float4* p = sent + ((size_t)b * LQ + (size_t)qc * 64) * D4 + d4;
    float4 acc = make_float4(0.f, 0.f, 0.f, 0.f);
#pragma unroll 4
    for (int q = 0; q < 64; ++q) {
        float4 v = p[(size_t)q * D4];
        acc.x += v.x; acc.y += v.y; acc.z += v.z; acc.w += v.w;
    }
    float* dst = s_sum + b * D + d4 * 4;
    atomicAdd(dst + 0, acc.x);
    atomicAdd(dst + 1, acc.y);
    atomicAdd(dst + 2, acc.z);
    atomicAdd(dst + 3, acc.w);
}

// ---------------- K2a / K6: y[b,e] = dot(x[b,:], W[e,:]) + bias_scale*bias[e]
// wave-per-output; grid 6144 blocks of 256 (4 waves), 24576 outputs.
__global__ __launch_bounds__(256) void k_rowdot(const float4* __restrict__ x4,
                                                const float4* __restrict__ W4,
                                                const float* __restrict__ bias,
                                                float bias_scale,
                                                float* __restrict__ y) {
    int w = blockIdx.x * 4 + (threadIdx.x >> 6);   // 0..24575
    int lane = threadIdx.x & 63;
    int b = w / D, e = w % D;
    const float4* xr = x4 + (size_t)b * D4;
    const float4* wr = W4 + (size_t)e * D4;
    float acc = 0.f;
#pragma unroll
    for (int i = 0; i < 3; ++i) {
        int idx = lane + i * 64;
        float4 a = xr[idx], q = wr[idx];
        acc += a.x * q.x + a.y * q.y + a.z * q.z + a.w * q.w;
    }
#pragma unroll
    for (int off = 32; off; off >>= 1) acc += __shfl_down(acc, off, 64);
    if (lane == 0) y[w] = acc + bias_scale * bias[e];
}

// ---------------- K2b: wk[b,d] = sum_e q_sum[b,e] * Wk[e,d] ----------------
// column access on Wk is coalesced across threads. grid (32,3), block 256.
__global__ __launch_bounds__(256) void k_qsum_Wk(const float* __restrict__ q_sum,
                                                 const float* __restrict__ Wk,
                                                 float* __restrict__ wk) {
    int b = blockIdx.x;
    int d = blockIdx.y * 256 + threadIdx.x;
    const float* qs = q_sum + b * D;
    float acc = 0.f;
#pragma unroll 8
    for (int e = 0; e < D; ++e)
        acc += qs[e] * Wk[(size_t)e * D + d];
    wk[b * D + d] = acc;
}

// ---------------- K3: scores[b,k] = dot(comment[b,k,:], wk[b,:]) ----------
// wave per (b,k); 65536 waves -> 16384 blocks of 256.
__global__ __launch_bounds__(256) void k_scores(const float4* __restrict__ com4,
                                                const float4* __restrict__ wk4,
                                                float* __restrict__ scores) {
    int w = blockIdx.x * 4 + (threadIdx.x >> 6);   // 0..65535
    int lane = threadIdx.x & 63;
    int b = w >> 11, k = w & 2047;
    const float4* c = com4 + ((size_t)b * LK + k) * D4;
    const float4* q = wk4 + (size_t)b * D4;
    float acc = 0.f;
#pragma unroll
    for (int i = 0; i < 3; ++i) {
        int idx = lane + i * 64;
        float4 a = c[idx], v = q[idx];
        acc += a.x * v.x + a.y * v.y + a.z * v.z + a.w * v.w;
    }
#pragma unroll
    for (int off = 32; off; off >>= 1) acc += __shfl_down(acc, off, 64);
    if (lane == 0) scores[w] = acc;
}

// ---------------- K4: softmax over k (2048) per b ----------------
__global__ __launch_bounds__(256) void k_softmax(const float* __restrict__ scores,
                                                 float* __restrict__ alpha) {
    __shared__ float redm[4];
    __shared__ float reds[4];
    int b = blockIdx.x, tid = threadIdx.x;
    int lane = tid & 63, wid = tid >> 6;
    const float* s = scores + b * LK;
    float v[8];
    float m = -INFINITY;
#pragma unroll
    for (int i = 0; i < 8; ++i) { v[i] = s[tid + i * 256]; m = fmaxf(m, v[i]); }
#pragma unroll
    for (int off = 1; off < 64; off <<= 1) m = fmaxf(m, __shfl_xor(m, off, 64));
    if (lane == 0) redm[wid] = m;
    __syncthreads();
    float mall = fmaxf(fmaxf(redm[0], redm[1]), fmaxf(redm[2], redm[3]));
    float part = 0.f;
    float e[8];
#pragma unroll
    for (int i = 0; i < 8; ++i) { e[i] = expf(v[i] - mall); part += e[i]; }
#pragma unroll
    for (int off = 1; off < 64; off <<= 1) part += __shfl_xor(part, off, 64);
    if (lane == 0) reds[wid] = part;
    __syncthreads();
    float total = reds[0] + reds[1] + reds[2] + reds[3];
    float inv = 1.f / total;
#pragma unroll
    for (int i = 0; i < 8; ++i) alpha[b * LK + tid + i * 256] = e[i] * inv;
}

// ---------------- K5: ctx[b,e] = sum_k alpha[b,k] * comment[b,k,e] --------
// grid (32, 8), block 192, atomicAdd partials.
__global__ __launch_bounds__(192) void k_ctx(const float4* __restrict__ com4,
                                             const float* __restrict__ alpha,
                                             float* __restrict__ ctx) {
    int b = blockIdx.x, kc = blockIdx.y;
    int e4 = threadIdx.x;
    const float4* c = com4 + ((size_t)b * LK + (size_t)kc * 256) * D4 + e4;
    const float* a = alpha + b * LK + kc * 256;
    float4 acc = make_float4(0.f, 0.f, 0.f, 0.f);
#pragma unroll 4
    for (int k = 0; k < 256; ++k) {
        float w = a[k];
        float4 v = c[(size_t)k * D4];
        acc.x += w * v.x; acc.y += w * v.y; acc.z += w * v.z; acc.w += w * v.w;
    }
    float* dst = ctx + b * D + e4 * 4;
    atomicAdd(dst + 0, acc.x);
    atomicAdd(dst + 1, acc.y);
    atomicAdd(dst + 2, acc.z);
    atomicAdd(dst + 3, acc.w);
}

extern "C" void kernel_launch(void* const* d_in, const int* in_sizes, int n_in,
                              void* d_out, int out_size, void* d_ws, size_t ws_size,
                              hipStream_t stream) {
    const float* sent = (const float*)d_in[0];   // [32,512,768]
    const float* com  = (const float*)d_in[1];   // [32,2048,768]
    const float* Wq   = (const float*)d_in[2];   // [768,768]
    const float* bq   = (const float*)d_in[3];   // [768]
    const float* Wk   = (const float*)d_in[4];
    // d_in[5] = bk: dropped (softmax-invariant constant per b)
    const float* Wv   = (const float*)d_in[6];
    const float* bv   = (const float*)d_in[7];
    float* out = (float*)d_out;

    // workspace layout (floats)
    float* ws = (float*)d_ws;
    float* s_sum  = ws;                 // 24576   (zeroed)
    float* ctx    = ws + 24576;         // 24576   (zeroed)
    float* q_sum  = ws + 49152;         // 24576
    float* wk     = ws + 73728;         // 24576
    float* scores = ws + 98304;         // 65536
    float* alpha  = ws + 163840;        // 65536

    // zero the two atomic accumulators (s_sum, ctx are adjacent)
    hipMemsetAsync(s_sum, 0, 2 * 24576 * sizeof(float), stream);

    // K1: sum sentence_rep over q
    k_sum_sent<<<dim3(B, 8), 192, 0, stream>>>((const float4*)sent, s_sum);

    // K2a: q_sum = s_sum @ Wq^T + 512*bq
    k_rowdot<<<6144, 256, 0, stream>>>((const float4*)s_sum, (const float4*)Wq,
                                       bq, (float)LQ, q_sum);

    // K2b: wk = q_sum @ Wk   (column-major access, coalesced)
    k_qsum_Wk<<<dim3(B, 3), 256, 0, stream>>>(q_sum, Wk, wk);

    // K3: scores
    k_scores<<<16384, 256, 0, stream>>>((const float4*)com, (const float4*)wk, scores);

    // K4: softmax
    k_softmax<<<B, 256, 0, stream>>>(scores, alpha);

    // K5: ctx = alpha-weighted sum of comment rows
    k_ctx<<<dim3(B, 8), 192, 0, stream>>>((const float4*)com, alpha, ctx);

    // K6: out = ctx @ Wv^T + bv
    k_rowdot<<<6144, 256, 0, stream>>>((const float4*)ctx, (const float4*)Wv,
                                       bv, 1.0f, out);
}

// Round 4
// 399.298 us; speedup vs baseline: 1.0417x; 1.0417x over previous
//
#include <hip/hip_runtime.h>
#include <math.h>

#define B 32
#define LQ 512
#define LK 2048
#define D 768
#define D4 192   // D/4 float4s per row
#define NC 32    // k-chunks per batch (split-K for fused attention)
// rows per chunk = LK/NC = 64; rows per wave = 16 (4 waves/block)

// ---------------- K1: s_sum[b,d] = sum_q sentence[b,q,d] ----------------
// grid (32, 32), block 192; each block sums 16 q-rows, atomicAdd partials.
__global__ __launch_bounds__(192) void k_sum_sent(const float4* __restrict__ sent,
                                                  float* __restrict__ s_sum) {
    int b = blockIdx.x, qc = blockIdx.y;
    int d4 = threadIdx.x;  // 0..191
    const float4* p = sent + ((size_t)b * LQ + (size_t)qc * 16) * D4 + d4;
    float4 acc = make_float4(0.f, 0.f, 0.f, 0.f);
#pragma unroll
    for (int q = 0; q < 16; ++q) {
        float4 v = p[(size_t)q * D4];
        acc.x += v.x; acc.y += v.y; acc.z += v.z; acc.w += v.w;
    }
    float* dst = s_sum + b * D + d4 * 4;
    atomicAdd(dst + 0, acc.x);
    atomicAdd(dst + 1, acc.y);
    atomicAdd(dst + 2, acc.z);
    atomicAdd(dst + 3, acc.w);
}

// ---------------- K2a / K6: y[b,e] = dot(x[b,:], W[e,:]) + bias_scale*bias[e]
__global__ __launch_bounds__(256) void k_rowdot(const float4* __restrict__ x4,
                                                const float4* __restrict__ W4,
                                                const float* __restrict__ bias,
                                                float bias_scale,
                                                float* __restrict__ y) {
    int w = blockIdx.x * 4 + (threadIdx.x >> 6);   // 0..24575
    int lane = threadIdx.x & 63;
    int b = w / D, e = w % D;
    const float4* xr = x4 + (size_t)b * D4;
    const float4* wr = W4 + (size_t)e * D4;
    float acc = 0.f;
#pragma unroll
    for (int i = 0; i < 3; ++i) {
        int idx = lane + i * 64;
        float4 a = xr[idx], q = wr[idx];
        acc += a.x * q.x + a.y * q.y + a.z * q.z + a.w * q.w;
    }
#pragma unroll
    for (int off = 32; off; off >>= 1) acc += __shfl_down(acc, off, 64);
    if (lane == 0) y[w] = acc + bias_scale * bias[e];
}

// ---------------- K2b: wk[b,d] = sum_e q_sum[b,e] * Wk[e,d] ----------------
__global__ __launch_bounds__(256) void k_qsum_Wk(const float* __restrict__ q_sum,
                                                 const float* __restrict__ Wk,
                                                 float* __restrict__ wk) {
    int b = blockIdx.x;
    int d = blockIdx.y * 256 + threadIdx.x;
    const float* qs = q_sum + b * D;
    float acc = 0.f;
#pragma unroll 8
    for (int e = 0; e < D; ++e)
        acc += qs[e] * Wk[(size_t)e * D + d];
    wk[b * D + d] = acc;
}

// ---------------- K3: fused scores + online softmax + weighted sum --------
// grid (32, NC), block 256 (4 waves). Each wave: 16 comment rows, kept in
// registers; online-softmax state (m, l, 768-wide acc as 3 float4/lane).
// Block-combines 4 waves in LDS; writes one partial (v[768], m, l) per chunk.
__global__ __launch_bounds__(256) void k_attn(const float4* __restrict__ com4,
                                              const float* __restrict__ wk,
                                              float* __restrict__ pv,
                                              float* __restrict__ pm,
                                              float* __restrict__ pl) {
    __shared__ float sm[4], sl[4];
    __shared__ float sacc[4][D];
    int b = blockIdx.x, chunk = blockIdx.y;
    int tid = threadIdx.x, lane = tid & 63, w = tid >> 6;

    const float4* q4 = (const float4*)(wk + (size_t)b * D);
    float4 q0 = q4[lane], q1 = q4[lane + 64], q2 = q4[lane + 128];

    int row0 = chunk * 64 + w * 16;
    const float4* base = com4 + ((size_t)b * LK + row0) * D4;

    float m = -INFINITY, l = 0.f;
    float4 A0 = make_float4(0.f, 0.f, 0.f, 0.f);
    float4 A1 = make_float4(0.f, 0.f, 0.f, 0.f);
    float4 A2 = make_float4(0.f, 0.f, 0.f, 0.f);

    for (int r = 0; r < 16; ++r) {
        float4 c0 = base[(size_t)r * D4 + lane];
        float4 c1 = base[(size_t)r * D4 + lane + 64];
        float4 c2 = base[(size_t)r * D4 + lane + 128];
        float s = c0.x * q0.x + c0.y * q0.y + c0.z * q0.z + c0.w * q0.w
                + c1.x * q1.x + c1.y * q1.y + c1.z * q1.z + c1.w * q1.w
                + c2.x * q2.x + c2.y * q2.y + c2.z * q2.z + c2.w * q2.w;
#pragma unroll
        for (int off = 32; off; off >>= 1) s += __shfl_xor(s, off, 64);
        if (s <= m) {                       // wave-uniform branch
            float p = __expf(s - m);
            l += p;
            A0.x += p * c0.x; A0.y += p * c0.y; A0.z += p * c0.z; A0.w += p * c0.w;
            A1.x += p * c1.x; A1.y += p * c1.y; A1.z += p * c1.z; A1.w += p * c1.w;
            A2.x += p * c2.x; A2.y += p * c2.y; A2.z += p * c2.z; A2.w += p * c2.w;
        } else {                            // new max: rescale (exp(-inf)=0 on iter 0)
            float f = __expf(m - s);
            l = l * f + 1.f;
            A0.x = A0.x * f + c0.x; A0.y = A0.y * f + c0.y; A0.z = A0.z * f + c0.z; A0.w = A0.w * f + c0.w;
            A1.x = A1.x * f + c1.x; A1.y = A1.y * f + c1.y; A1.z = A1.z * f + c1.z; A1.w = A1.w * f + c1.w;
            A2.x = A2.x * f + c2.x; A2.y = A2.y * f + c2.y; A2.z = A2.z * f + c2.z; A2.w = A2.w * f + c2.w;
            m = s;
        }
    }

    if (lane == 0) { sm[w] = m; sl[w] = l; }
    float4* sa = (float4*)sacc[w];
    sa[lane] = A0; sa[lane + 64] = A1; sa[lane + 128] = A2;
    __syncthreads();

    float M = fmaxf(fmaxf(sm[0], sm[1]), fmaxf(sm[2], sm[3]));
    float e0 = __expf(sm[0] - M), e1 = __expf(sm[1] - M);
    float e2 = __expf(sm[2] - M), e3 = __expf(sm[3] - M);
    float L = sl[0] * e0 + sl[1] * e1 + sl[2] * e2 + sl[3] * e3;

    int col = tid * 3;  // 256 threads x 3 cols = 768
    float* dst = pv + ((size_t)b * NC + chunk) * D;
#pragma unroll
    for (int j = 0; j < 3; ++j) {
        int c = col + j;
        dst[c] = sacc[0][c] * e0 + sacc[1][c] * e1 + sacc[2][c] * e2 + sacc[3][c] * e3;
    }
    if (tid == 0) { pm[b * NC + chunk] = M; pl[b * NC + chunk] = L; }
}

// ---------------- K4: merge split-K partials -> ctx[b,e] ----------------
__global__ __launch_bounds__(256) void k_merge(const float* __restrict__ pv,
                                               const float* __restrict__ pm,
                                               const float* __restrict__ pl,
                                               float* __restrict__ ctx) {
    __shared__ float spm[NC], spl[NC];
    int b = blockIdx.x, tid = threadIdx.x;
    if (tid < NC) { spm[tid] = pm[b * NC + tid]; spl[tid] = pl[b * NC + tid]; }
    __syncthreads();
    float M = -INFINITY;
#pragma unroll
    for (int c = 0; c < NC; ++c) M = fmaxf(M, spm[c]);
    float L = 0.f;
#pragma unroll
    for (int c = 0; c < NC; ++c) L += spl[c] * __expf(spm[c] - M);
    float inv = 1.f / L;
    int col = tid * 3;
    float o0 = 0.f, o1 = 0.f, o2 = 0.f;
    for (int c = 0; c < NC; ++c) {
        float e = __expf(spm[c] - M);
        const float* p = pv + ((size_t)b * NC + c) * D + col;
        o0 += e * p[0]; o1 += e * p[1]; o2 += e * p[2];
    }
    ctx[b * D + col] = o0 * inv;
    ctx[b * D + col + 1] = o1 * inv;
    ctx[b * D + col + 2] = o2 * inv;
}

extern "C" void kernel_launch(void* const* d_in, const int* in_sizes, int n_in,
                              void* d_out, int out_size, void* d_ws, size_t ws_size,
                              hipStream_t stream) {
    const float* sent = (const float*)d_in[0];   // [32,512,768]
    const float* com  = (const float*)d_in[1];   // [32,2048,768]
    const float* Wq   = (const float*)d_in[2];   // [768,768]
    const float* bq   = (const float*)d_in[3];   // [768]
    const float* Wk   = (const float*)d_in[4];
    // d_in[5] = bk: dropped (softmax-invariant constant per b)
    const float* Wv   = (const float*)d_in[6];
    const float* bv   = (const float*)d_in[7];
    float* out = (float*)d_out;

    // workspace layout (floats)
    float* ws = (float*)d_ws;
    float* s_sum = ws;                  // 24576 (zeroed, atomics)
    float* q_sum = ws + 24576;          // 24576
    float* wk    = ws + 49152;          // 24576
    float* ctx   = ws + 73728;          // 24576
    float* pm    = ws + 98304;          // 1024
    float* pl    = ws + 99328;          // 1024
    float* pv    = ws + 100352;         // 32*32*768 = 786432

    hipMemsetAsync(s_sum, 0, 24576 * sizeof(float), stream);

    // K1: sum sentence_rep over q
    k_sum_sent<<<dim3(B, 32), 192, 0, stream>>>((const float4*)sent, s_sum);

    // K2a: q_sum = s_sum @ Wq^T + 512*bq
    k_rowdot<<<6144, 256, 0, stream>>>((const float4*)s_sum, (const float4*)Wq,
                                       bq, (float)LQ, q_sum);

    // K2b: wk = q_sum @ Wk
    k_qsum_Wk<<<dim3(B, 3), 256, 0, stream>>>(q_sum, Wk, wk);

    // K3: fused scores + online softmax + weighted sum (comment read ONCE)
    k_attn<<<dim3(B, NC), 256, 0, stream>>>((const float4*)com, wk, pv, pm, pl);

    // K4: merge partials -> ctx
    k_merge<<<B, 256, 0, stream>>>(pv, pm, pl, ctx);

    // K6: out = ctx @ Wv^T + bv
    k_rowdot<<<6144, 256, 0, stream>>>((const float4*)ctx, (const float4*)Wv,
                                       bv, 1.0f, out);
}